// Round 1
// baseline (1101.392 us; speedup 1.0000x reference)
//
#include <hip/hip_runtime.h>
#include <cstdio>
#include <cstdint>
#include <cstddef>

#define AS_GLOBAL __attribute__((address_space(1)))
#define AS_LDS    __attribute__((address_space(3)))

typedef __bf16 bf16x8 __attribute__((ext_vector_type(8)));
typedef float  f32x4  __attribute__((ext_vector_type(4)));

constexpr int OUT_F = 4096;
constexpr int IN_F  = 4096;
constexpr int MROWS = 8 * 2048;   // B*S = 16384

// ---------------------------------------------------------------------------
// Kernel 1: dequantize W_q (int32 u8 values, shape [64][262144] row-major)
// into bf16 W[o][i] row-major [4096][4096].
//   flat(Wq) = (o>>6)*2^18 + n,  group n = (o&63)*4096 + i
// 4 elements per thread, fully coalesced (consecutive i -> consecutive flat/n).
// ---------------------------------------------------------------------------
__global__ void dequant_w(const int* __restrict__ Wq, const float* __restrict__ scale,
                          const float* __restrict__ zero, __bf16* __restrict__ Wb) {
    int t   = blockIdx.x * blockDim.x + threadIdx.x;
    int idx = t * 4;                       // flat index into W[o][i]
    int o   = idx >> 12;
    int i   = idx & 4095;
    int n   = ((o & 63) << 12) | i;        // group index
    size_t flat = ((size_t)(o >> 6) << 18) + (size_t)n;
    int4   q = *(const int4*)(Wq + flat);
    float4 z = *(const float4*)(zero + n);
    float4 s = *(const float4*)(scale + n);
    __bf16 r[4];
    r[0] = (__bf16)(((float)q.x - z.x) * s.x);
    r[1] = (__bf16)(((float)q.y - z.y) * s.y);
    r[2] = (__bf16)(((float)q.z - z.z) * s.z);
    r[3] = (__bf16)(((float)q.w - z.w) * s.w);
    *(uint2*)(Wb + idx) = *(const uint2*)r;
}

// ---------------------------------------------------------------------------
// Kernel 2: x fp32 -> bf16 (halves GEMM A-panel fetch volume)
// ---------------------------------------------------------------------------
__global__ void convert_x(const float* __restrict__ x, __bf16* __restrict__ xb) {
    size_t t   = (size_t)blockIdx.x * blockDim.x + threadIdx.x;
    size_t idx = t * 8;
    float4 a = *(const float4*)(x + idx);
    float4 b = *(const float4*)(x + idx + 4);
    __bf16 r[8];
    r[0] = (__bf16)a.x; r[1] = (__bf16)a.y; r[2] = (__bf16)a.z; r[3] = (__bf16)a.w;
    r[4] = (__bf16)b.x; r[5] = (__bf16)b.y; r[6] = (__bf16)b.z; r[7] = (__bf16)b.w;
    *(uint4*)(xb + idx) = *(const uint4*)r;
}

// ---------------------------------------------------------------------------
// Kernel 3: C[M][N] = A[M][K] * B[N][K]^T + bias   (bf16 in, fp32 out)
// m97-style: 128x128 tile, BK=32, 256 threads (4 waves 2x2), each wave a
// 64x64 quadrant = 4x4 tiles of mfma_f32_16x16x32_bf16.
// Staging via global_load_lds width=16: LDS dest is wave-uniform base +
// lane*16, so LDS layout is plain row-major [128][32] bf16, no padding.
// ---------------------------------------------------------------------------
__device__ __forceinline__ void load16_to_lds(const void* g, void* lds) {
    __builtin_amdgcn_global_load_lds((AS_GLOBAL void*)g, (AS_LDS void*)lds, 16, 0, 0);
}

__global__ __launch_bounds__(256) void gemm_bt_bias(
    const __bf16* __restrict__ A,   // [M][K]
    const __bf16* __restrict__ B,   // [N][K]
    const float*  __restrict__ bias,
    float*        __restrict__ C)   // [M][N]
{
    constexpr int K = IN_F, N = OUT_F;
    constexpr int BKt = 32;
    __shared__ __align__(16) __bf16 sA[128 * BKt];   // 8 KB
    __shared__ __align__(16) __bf16 sB[128 * BKt];   // 8 KB

    const int tid  = threadIdx.x;
    const int lane = tid & 63;
    const int w    = tid >> 6;       // wave 0..3
    const int wr   = w >> 1;         // wave row (0..1)
    const int wc   = w & 1;          // wave col (0..1)
    const int m0   = blockIdx.y * 128;
    const int n0   = blockIdx.x * 128;

    f32x4 acc[4][4] = {};

    // Staging: 16B chunk c = tid covers tile row (c>>2), col chunk (c&3)*8.
    // Issue 0: chunks 0..255 (rows 0..63); issue 1: chunks 256..511 (rows 64..127).
    const int r0 = tid >> 2;
    const int cc = (tid & 3) * 8;
    const __bf16* gA0 = A + (size_t)(m0 + r0) * K + cc;
    const __bf16* gA1 = gA0 + (size_t)64 * K;
    const __bf16* gB0 = B + (size_t)(n0 + r0) * K + cc;
    const __bf16* gB1 = gB0 + (size_t)64 * K;
    // wave-uniform LDS bases: wave w's 64 lanes fill bytes [w*1024, w*1024+1024)
    char* sAb = (char*)sA + w * 1024;
    char* sBb = (char*)sB + w * 1024;

    // Fragment addressing: lane holds A[m=lane&15][k=(lane>>4)*8 + j]
    const int fr = lane & 15;
    const int fk = (lane >> 4) * 8;

    for (int k0 = 0; k0 < K; k0 += BKt) {
        __syncthreads();                       // prev iter's LDS reads done
        load16_to_lds(gA0 + k0, sAb);
        load16_to_lds(gA1 + k0, sAb + 4096);
        load16_to_lds(gB0 + k0, sBb);
        load16_to_lds(gB1 + k0, sBb + 4096);
        __syncthreads();                       // compiler drains vmcnt before barrier

        bf16x8 aF[4], bF[4];
#pragma unroll
        for (int mi = 0; mi < 4; ++mi)
            aF[mi] = *(const bf16x8*)(sA + (wr * 64 + mi * 16 + fr) * BKt + fk);
#pragma unroll
        for (int ni = 0; ni < 4; ++ni)
            bF[ni] = *(const bf16x8*)(sB + (wc * 64 + ni * 16 + fr) * BKt + fk);
#pragma unroll
        for (int mi = 0; mi < 4; ++mi)
#pragma unroll
            for (int ni = 0; ni < 4; ++ni)
                acc[mi][ni] = __builtin_amdgcn_mfma_f32_16x16x32_bf16(
                    aF[mi], bF[ni], acc[mi][ni], 0, 0, 0);
    }

    // Epilogue: C/D layout col=lane&15, row=(lane>>4)*4+reg  [m89-verified]
    const int rb = (lane >> 4) * 4;
    const int cl = lane & 15;
#pragma unroll
    for (int ni = 0; ni < 4; ++ni) {
        const int   c  = n0 + wc * 64 + ni * 16 + cl;
        const float bv = bias[c];
#pragma unroll
        for (int mi = 0; mi < 4; ++mi) {
            const size_t base = (size_t)(m0 + wr * 64 + mi * 16 + rb) * N + c;
#pragma unroll
            for (int rg = 0; rg < 4; ++rg)
                C[base + (size_t)rg * N] = acc[mi][ni][rg] + bv;
        }
    }
}

// ---------------------------------------------------------------------------
extern "C" void kernel_launch(void* const* d_in, const int* in_sizes, int n_in,
                              void* d_out, int out_size, void* d_ws, size_t ws_size,
                              hipStream_t stream) {
    const float* x     = (const float*)d_in[0];   // [8,2048,4096] fp32
    const int*   Wq    = (const int*)d_in[1];     // [64,262144] int32
    const float* scale = (const float*)d_in[2];   // [1,262144]
    const float* zero  = (const float*)d_in[3];   // [1,262144]
    const float* bias  = (const float*)d_in[4];   // [4096]
    float* out = (float*)d_out;                   // [8,2048,4096] fp32

    const size_t wbytes = (size_t)OUT_F * IN_F * 2;   // 33.6 MB bf16 W
    const size_t xbytes = (size_t)MROWS * IN_F * 2;   // 134 MB bf16 x
    if (ws_size < wbytes + xbytes) {
        fprintf(stderr, "kernel_launch: ws_size=%zu < needed %zu — aborting\n",
                ws_size, wbytes + xbytes);
        return;
    }
    __bf16* Wb = (__bf16*)d_ws;
    __bf16* xb = (__bf16*)((char*)d_ws + wbytes);

    dequant_w<<<(OUT_F * IN_F / 4) / 256, 256, 0, stream>>>(Wq, scale, zero, Wb);
    convert_x<<<((size_t)MROWS * IN_F / 8) / 256, 256, 0, stream>>>(x, xb);

    dim3 grid(OUT_F / 128, MROWS / 128);   // (32, 128) = 4096 blocks
    gemm_bt_bias<<<grid, 256, 0, stream>>>(xb, Wb, bias, out);
}